// Round 1
// baseline (455.427 us; speedup 1.0000x reference)
//
#include <hip/hip_runtime.h>
#include <stdint.h>

typedef unsigned short u16;
typedef float f32x4 __attribute__((ext_vector_type(4)));
typedef short s16x8 __attribute__((ext_vector_type(8)));

#define SEQ 2048
#define DM 1024
#define NH 16
#define HD 64
#define BATCH 4
#define ROWS (BATCH*SEQ)   // 8192

__device__ __forceinline__ u16 f32_bf16(float f) {
  union { float f; uint32_t u; } c; c.f = f;
  uint32_t u = c.u;
  return (u16)((u + 0x7fffu + ((u >> 16) & 1u)) >> 16);  // RNE
}

// ---------------- cast kernels ----------------
__global__ __launch_bounds__(256) void cast_bf16_k(const float* __restrict__ in,
                                                   u16* __restrict__ out, int n4) {
  int i = blockIdx.x * 256 + threadIdx.x;
  if (i >= n4) return;
  float4 v = ((const float4*)in)[i];
  ushort4 o;
  o.x = f32_bf16(v.x); o.y = f32_bf16(v.y); o.z = f32_bf16(v.z); o.w = f32_bf16(v.w);
  ((ushort4*)out)[i] = o;
}

// in [R][C] fp32  ->  out [C][R] bf16
__global__ __launch_bounds__(256) void cast_transpose_k(const float* __restrict__ in,
                                                        u16* __restrict__ out, int R, int C) {
  __shared__ float tile[32][33];
  int c0 = blockIdx.x * 32, r0 = blockIdx.y * 32;
  int t = threadIdx.x;
  int lr = t >> 3, lc = (t & 7) * 4;
  float4 v = *(const float4*)(in + (size_t)(r0 + lr) * C + c0 + lc);
  tile[lr][lc] = v.x; tile[lr][lc + 1] = v.y; tile[lr][lc + 2] = v.z; tile[lr][lc + 3] = v.w;
  __syncthreads();
  ushort4 o;
  o.x = f32_bf16(tile[lc + 0][lr]);
  o.y = f32_bf16(tile[lc + 1][lr]);
  o.z = f32_bf16(tile[lc + 2][lr]);
  o.w = f32_bf16(tile[lc + 3][lr]);
  *(ushort4*)(out + (size_t)(c0 + lr) * R + r0 + lc) = o;
}

// ---------------- GEMM: C[M,N] = A[M,K] * Bt[N,K]^T, bf16 in, fp32 acc ----------------
// EPI 0: plain fp32 store. EPI 1: QKV scatter to [B,H,T,HD] bf16, Q pre-scaled by 0.125.
template<int EPI>
__global__ __launch_bounds__(256) void gemm_bt(
    const u16* __restrict__ A, const u16* __restrict__ Bt,
    float* __restrict__ Cf, u16* __restrict__ Qo, u16* __restrict__ Ko, u16* __restrict__ Vo,
    int M, int N, int K)
{
  // stride 40: 80B rows -> 16B-aligned b128 ops, <=2-way bank aliasing on frag reads
  __shared__ u16 As[128][40];
  __shared__ u16 Bs[128][40];
  int t = threadIdx.x;
  int m0 = blockIdx.y * 128, n0 = blockIdx.x * 128;
  int srow = t >> 1, scol = (t & 1) * 16;
  const u16* Ab = A + (size_t)(m0 + srow) * K + scol;
  const u16* Bb = Bt + (size_t)(n0 + srow) * K + scol;
  int lane = t & 63, w = t >> 6;
  int m16 = lane & 15, quad = lane >> 4;
  int wr = (w >> 1) * 64, wc = (w & 1) * 64;

  f32x4 acc[4][4];
#pragma unroll
  for (int mi = 0; mi < 4; ++mi)
#pragma unroll
    for (int ni = 0; ni < 4; ++ni)
#pragma unroll
      for (int r = 0; r < 4; ++r) acc[mi][ni][r] = 0.f;

  for (int k0 = 0; k0 < K; k0 += 32) {
    uint4 a0 = *(const uint4*)(Ab + k0);
    uint4 a1 = *(const uint4*)(Ab + k0 + 8);
    uint4 b0 = *(const uint4*)(Bb + k0);
    uint4 b1 = *(const uint4*)(Bb + k0 + 8);
    __syncthreads();
    *(uint4*)&As[srow][scol]     = a0;
    *(uint4*)&As[srow][scol + 8] = a1;
    *(uint4*)&Bs[srow][scol]     = b0;
    *(uint4*)&Bs[srow][scol + 8] = b1;
    __syncthreads();
    s16x8 af[4], bf[4];
#pragma unroll
    for (int mi = 0; mi < 4; ++mi) af[mi] = *(const s16x8*)&As[wr + mi * 16 + m16][quad * 8];
#pragma unroll
    for (int ni = 0; ni < 4; ++ni) bf[ni] = *(const s16x8*)&Bs[wc + ni * 16 + m16][quad * 8];
#pragma unroll
    for (int mi = 0; mi < 4; ++mi)
#pragma unroll
      for (int ni = 0; ni < 4; ++ni)
        acc[mi][ni] = __builtin_amdgcn_mfma_f32_16x16x32_bf16(af[mi], bf[ni], acc[mi][ni], 0, 0, 0);
  }

  if (EPI == 0) {
#pragma unroll
    for (int mi = 0; mi < 4; ++mi) {
      int gr = m0 + wr + mi * 16 + quad * 4;
#pragma unroll
      for (int ni = 0; ni < 4; ++ni) {
        int gc = n0 + wc + ni * 16 + m16;
#pragma unroll
        for (int r = 0; r < 4; ++r)
          Cf[(size_t)(gr + r) * N + gc] = acc[mi][ni][r];
      }
    }
  } else {
#pragma unroll
    for (int mi = 0; mi < 4; ++mi) {
      int gr = m0 + wr + mi * 16 + quad * 4;
#pragma unroll
      for (int ni = 0; ni < 4; ++ni) {
        int gc = n0 + wc + ni * 16 + m16;
        int sec = gc >> 10, rem = gc & 1023, h = rem >> 6, d = rem & 63;
#pragma unroll
        for (int r = 0; r < 4; ++r) {
          int grr = gr + r;
          int b = grr >> 11, tt = grr & 2047;
          size_t dst = (((size_t)b * NH + h) * SEQ + tt) * HD + d;
          float v = acc[mi][ni][r];
          if (sec == 0)      Qo[dst] = f32_bf16(v * 0.125f);   // fold 1/sqrt(64) into Q
          else if (sec == 1) Ko[dst] = f32_bf16(v);
          else               Vo[dst] = f32_bf16(v);
        }
      }
    }
  }
}

// ---------------- flash attention, causal ----------------
// grid (SEQ/64, B*H); block 256 = 4 waves; wave w owns q rows [q0+16w, q0+16w+16)
__global__ __launch_bounds__(256) void attn_k(
    const u16* __restrict__ Q, const u16* __restrict__ K,
    const u16* __restrict__ V, u16* __restrict__ O)
{
  __shared__ u16 Ks[64][72];      // [key][d]
  __shared__ u16 Vt[64][72];      // [d][key]
  __shared__ u16 Ps[4][16][72];   // per wave: [qrow][key]
  int bh = blockIdx.y, qt = blockIdx.x;
  int q0 = qt * 64;
  int t = threadIdx.x, w = t >> 6, lane = t & 63;
  int m16 = lane & 15, quad = lane >> 4;

  const u16* Qb = Q + ((size_t)bh * SEQ + q0 + w * 16 + m16) * HD + quad * 8;
  s16x8 qf0 = *(const s16x8*)Qb;
  s16x8 qf1 = *(const s16x8*)(Qb + 32);

  f32x4 acco[4];
  float m_run[4], l_run[4];
#pragma unroll
  for (int r = 0; r < 4; ++r) { m_run[r] = -1e30f; l_run[r] = 0.f; }
#pragma unroll
  for (int ni = 0; ni < 4; ++ni)
#pragma unroll
    for (int r = 0; r < 4; ++r) acco[ni][r] = 0.f;

  int srow = t >> 2, sc = (t & 3) * 16;
  const u16* Kg0 = K + ((size_t)bh * SEQ + srow) * HD + sc;
  const u16* Vg0 = V + ((size_t)bh * SEQ + srow) * HD + sc;

  for (int kt = 0; kt <= qt; ++kt) {
    uint4 kv0 = *(const uint4*)(Kg0 + (size_t)kt * 64 * HD);
    uint4 kv1 = *(const uint4*)(Kg0 + (size_t)kt * 64 * HD + 8);
    union { uint4 q; u16 u[8]; } uv0, uv1;
    uv0.q = *(const uint4*)(Vg0 + (size_t)kt * 64 * HD);
    uv1.q = *(const uint4*)(Vg0 + (size_t)kt * 64 * HD + 8);
    __syncthreads();   // previous iter's LDS reads done
    *(uint4*)&Ks[srow][sc]     = kv0;
    *(uint4*)&Ks[srow][sc + 8] = kv1;
#pragma unroll
    for (int i = 0; i < 8; ++i) {
      Vt[sc + i][srow]     = uv0.u[i];
      Vt[sc + 8 + i][srow] = uv1.u[i];
    }
    __syncthreads();

    // S = Q K^T  (scale pre-folded into Q)
    f32x4 sacc[4];
#pragma unroll
    for (int ni = 0; ni < 4; ++ni)
#pragma unroll
      for (int r = 0; r < 4; ++r) sacc[ni][r] = 0.f;
#pragma unroll
    for (int ni = 0; ni < 4; ++ni) {
      s16x8 kf0 = *(const s16x8*)&Ks[ni * 16 + m16][quad * 8];
      s16x8 kf1 = *(const s16x8*)&Ks[ni * 16 + m16][32 + quad * 8];
      sacc[ni] = __builtin_amdgcn_mfma_f32_16x16x32_bf16(qf0, kf0, sacc[ni], 0, 0, 0);
      sacc[ni] = __builtin_amdgcn_mfma_f32_16x16x32_bf16(qf1, kf1, sacc[ni], 0, 0, 0);
    }
    if (kt == qt) {  // diagonal tile: causal mask
#pragma unroll
      for (int ni = 0; ni < 4; ++ni)
#pragma unroll
        for (int r = 0; r < 4; ++r) {
          int qrow = w * 16 + quad * 4 + r;
          int kcol = ni * 16 + m16;
          if (kcol > qrow) sacc[ni][r] = -1e30f;
        }
    }
    float rowm[4];
#pragma unroll
    for (int r = 0; r < 4; ++r) rowm[r] = -1e30f;
#pragma unroll
    for (int ni = 0; ni < 4; ++ni)
#pragma unroll
      for (int r = 0; r < 4; ++r) rowm[r] = fmaxf(rowm[r], sacc[ni][r]);
#pragma unroll
    for (int off = 1; off < 16; off <<= 1)
#pragma unroll
      for (int r = 0; r < 4; ++r) rowm[r] = fmaxf(rowm[r], __shfl_xor(rowm[r], off, 64));

    float alpha[4], psum[4];
#pragma unroll
    for (int r = 0; r < 4; ++r) {
      float mn = fmaxf(m_run[r], rowm[r]);
      alpha[r] = __expf(m_run[r] - mn);
      m_run[r] = mn;
      psum[r] = 0.f;
    }
#pragma unroll
    for (int ni = 0; ni < 4; ++ni)
#pragma unroll
      for (int r = 0; r < 4; ++r) {
        float p = __expf(sacc[ni][r] - m_run[r]);
        psum[r] += p;
        Ps[w][quad * 4 + r][ni * 16 + m16] = f32_bf16(p);
      }
#pragma unroll
    for (int off = 1; off < 16; off <<= 1)
#pragma unroll
      for (int r = 0; r < 4; ++r) psum[r] += __shfl_xor(psum[r], off, 64);
#pragma unroll
    for (int r = 0; r < 4; ++r) l_run[r] = l_run[r] * alpha[r] + psum[r];
#pragma unroll
    for (int ni = 0; ni < 4; ++ni)
#pragma unroll
      for (int r = 0; r < 4; ++r) acco[ni][r] *= alpha[r];

    __syncthreads();  // make cross-lane P visible before A-layout reads
#pragma unroll
    for (int ks = 0; ks < 2; ++ks) {
      s16x8 pf = *(const s16x8*)&Ps[w][m16][ks * 32 + quad * 8];
#pragma unroll
      for (int ni = 0; ni < 4; ++ni) {
        s16x8 vf = *(const s16x8*)&Vt[ni * 16 + m16][ks * 32 + quad * 8];
        acco[ni] = __builtin_amdgcn_mfma_f32_16x16x32_bf16(pf, vf, acco[ni], 0, 0, 0);
      }
    }
  }

  // epilogue: O / l, write as [B][T][H*HD] bf16
  int b = bh >> 4, h = bh & 15;
#pragma unroll
  for (int r = 0; r < 4; ++r) {
    float inv = 1.f / l_run[r];
    int trow = q0 + w * 16 + quad * 4 + r;
    size_t base = ((size_t)(b * SEQ + trow)) * DM + h * HD;
#pragma unroll
    for (int ni = 0; ni < 4; ++ni)
      O[base + ni * 16 + m16] = f32_bf16(acco[ni][r] * inv);
  }
}

// ---------------- launch ----------------
extern "C" void kernel_launch(void* const* d_in, const int* in_sizes, int n_in,
                              void* d_out, int out_size, void* d_ws, size_t ws_size,
                              hipStream_t stream) {
  const float* x    = (const float*)d_in[0];   // [4,2048,1024]
  const float* Wqkv = (const float*)d_in[1];   // [1024,3072]
  const float* Wout = (const float*)d_in[2];   // [1024,1024]
  float* out = (float*)d_out;                  // [4,2048,1024] fp32

  // workspace layout (bf16 elements), total ~46.1M u16 = ~92 MB
  u16* ws = (u16*)d_ws;
  size_t off = 0;
  u16* x_bf   = ws + off; off += (size_t)ROWS * DM;          // x cast
  u16* wqkv_t = ws + off; off += (size_t)(3 * DM) * DM;      // W_qkv^T [3072][1024]
  u16* wout_t = ws + off; off += (size_t)DM * DM;            // W_out^T [1024][1024]
  u16* Qb     = ws + off; off += (size_t)BATCH * NH * SEQ * HD;
  u16* Kb     = ws + off; off += (size_t)BATCH * NH * SEQ * HD;
  u16* Vb     = ws + off; off += (size_t)BATCH * NH * SEQ * HD;
  u16* AO     = ws + off; off += (size_t)ROWS * DM;          // attention out [8192][1024]

  cast_bf16_k<<<(ROWS * DM / 4 + 255) / 256, 256, 0, stream>>>(x, x_bf, ROWS * DM / 4);
  cast_transpose_k<<<dim3(3 * DM / 32, DM / 32), 256, 0, stream>>>(Wqkv, wqkv_t, DM, 3 * DM);
  cast_transpose_k<<<dim3(DM / 32, DM / 32), 256, 0, stream>>>(Wout, wout_t, DM, DM);
  gemm_bt<1><<<dim3(3 * DM / 128, ROWS / 128), 256, 0, stream>>>(
      x_bf, wqkv_t, nullptr, Qb, Kb, Vb, ROWS, 3 * DM, DM);
  attn_k<<<dim3(SEQ / 64, BATCH * NH), 256, 0, stream>>>(Qb, Kb, Vb, AO);
  gemm_bt<0><<<dim3(DM / 128, ROWS / 128), 256, 0, stream>>>(
      AO, wout_t, out, nullptr, nullptr, nullptr, ROWS, DM, DM);
}

// Round 2
// 326.852 us; speedup vs baseline: 1.3934x; 1.3934x over previous
//
#include <hip/hip_runtime.h>
#include <stdint.h>

typedef unsigned short u16;
typedef float f32x4 __attribute__((ext_vector_type(4)));
typedef short s16x8 __attribute__((ext_vector_type(8)));

#define SEQ 2048
#define DM 1024
#define NH 16
#define HD 64
#define BATCH 4
#define ROWS (BATCH*SEQ)   // 8192
#define QTILES (SEQ/64)    // 32

__device__ __forceinline__ u16 f32_bf16(float f) {
  union { float f; uint32_t u; } c; c.f = f;
  uint32_t u = c.u;
  return (u16)((u + 0x7fffu + ((u >> 16) & 1u)) >> 16);  // RNE
}

// ---------------- cast kernels ----------------
__global__ __launch_bounds__(256) void cast_bf16_k(const float* __restrict__ in,
                                                   u16* __restrict__ out, int n4) {
  int i = blockIdx.x * 256 + threadIdx.x;
  if (i >= n4) return;
  float4 v = ((const float4*)in)[i];
  ushort4 o;
  o.x = f32_bf16(v.x); o.y = f32_bf16(v.y); o.z = f32_bf16(v.z); o.w = f32_bf16(v.w);
  ((ushort4*)out)[i] = o;
}

// in [R][C] fp32  ->  out [C][R] bf16
__global__ __launch_bounds__(256) void cast_transpose_k(const float* __restrict__ in,
                                                        u16* __restrict__ out, int R, int C) {
  __shared__ float tile[32][33];
  int c0 = blockIdx.x * 32, r0 = blockIdx.y * 32;
  int t = threadIdx.x;
  int lr = t >> 3, lc = (t & 7) * 4;
  float4 v = *(const float4*)(in + (size_t)(r0 + lr) * C + c0 + lc);
  tile[lr][lc] = v.x; tile[lr][lc + 1] = v.y; tile[lr][lc + 2] = v.z; tile[lr][lc + 3] = v.w;
  __syncthreads();
  ushort4 o;
  o.x = f32_bf16(tile[lc + 0][lr]);
  o.y = f32_bf16(tile[lc + 1][lr]);
  o.z = f32_bf16(tile[lc + 2][lr]);
  o.w = f32_bf16(tile[lc + 3][lr]);
  *(ushort4*)(out + (size_t)(c0 + lr) * R + r0 + lc) = o;
}

// ---------------- GEMM: C[M,N] = A[M,K] * Bt[N,K]^T, bf16 in, fp32 acc ----------------
// EPI 0: plain fp32 store.
// EPI 1: QKV scatter. Q -> [B,H,T,HD] bf16 (pre-scaled 0.125), K -> [B,H,T,HD],
//        V -> [B,H,HD,T] (TRANSPOSED so attn can stage Vt with b128 LDS writes).
template<int EPI>
__global__ __launch_bounds__(256) void gemm_bt(
    const u16* __restrict__ A, const u16* __restrict__ Bt,
    float* __restrict__ Cf, u16* __restrict__ Qo, u16* __restrict__ Ko, u16* __restrict__ Vo,
    int M, int N, int K)
{
  // stride 40: 80B rows -> 16B-aligned b128 ops, <=2-way bank aliasing on frag reads
  __shared__ u16 As[128][40];
  __shared__ u16 Bs[128][40];
  int t = threadIdx.x;
  int m0 = blockIdx.y * 128, n0 = blockIdx.x * 128;
  int srow = t >> 1, scol = (t & 1) * 16;
  const u16* Ab = A + (size_t)(m0 + srow) * K + scol;
  const u16* Bb = Bt + (size_t)(n0 + srow) * K + scol;
  int lane = t & 63, w = t >> 6;
  int m16 = lane & 15, quad = lane >> 4;
  int wr = (w >> 1) * 64, wc = (w & 1) * 64;

  f32x4 acc[4][4];
#pragma unroll
  for (int mi = 0; mi < 4; ++mi)
#pragma unroll
    for (int ni = 0; ni < 4; ++ni)
#pragma unroll
      for (int r = 0; r < 4; ++r) acc[mi][ni][r] = 0.f;

  for (int k0 = 0; k0 < K; k0 += 32) {
    uint4 a0 = *(const uint4*)(Ab + k0);
    uint4 a1 = *(const uint4*)(Ab + k0 + 8);
    uint4 b0 = *(const uint4*)(Bb + k0);
    uint4 b1 = *(const uint4*)(Bb + k0 + 8);
    __syncthreads();
    *(uint4*)&As[srow][scol]     = a0;
    *(uint4*)&As[srow][scol + 8] = a1;
    *(uint4*)&Bs[srow][scol]     = b0;
    *(uint4*)&Bs[srow][scol + 8] = b1;
    __syncthreads();
    s16x8 af[4], bf[4];
#pragma unroll
    for (int mi = 0; mi < 4; ++mi) af[mi] = *(const s16x8*)&As[wr + mi * 16 + m16][quad * 8];
#pragma unroll
    for (int ni = 0; ni < 4; ++ni) bf[ni] = *(const s16x8*)&Bs[wc + ni * 16 + m16][quad * 8];
#pragma unroll
    for (int mi = 0; mi < 4; ++mi)
#pragma unroll
      for (int ni = 0; ni < 4; ++ni)
        acc[mi][ni] = __builtin_amdgcn_mfma_f32_16x16x32_bf16(af[mi], bf[ni], acc[mi][ni], 0, 0, 0);
  }

  if (EPI == 0) {
#pragma unroll
    for (int mi = 0; mi < 4; ++mi) {
      int gr = m0 + wr + mi * 16 + quad * 4;
#pragma unroll
      for (int ni = 0; ni < 4; ++ni) {
        int gc = n0 + wc + ni * 16 + m16;
#pragma unroll
        for (int r = 0; r < 4; ++r)
          Cf[(size_t)(gr + r) * N + gc] = acc[mi][ni][r];
      }
    }
  } else {
#pragma unroll
    for (int mi = 0; mi < 4; ++mi) {
      int gr = m0 + wr + mi * 16 + quad * 4;   // multiple of 4, never crosses a batch bound
      int b = gr >> 11, tt = gr & 2047;
#pragma unroll
      for (int ni = 0; ni < 4; ++ni) {
        int gc = n0 + wc + ni * 16 + m16;
        int sec = gc >> 10, rem = gc & 1023, h = rem >> 6, d = rem & 63;
        if (sec == 0) {
#pragma unroll
          for (int r = 0; r < 4; ++r)
            Qo[(((size_t)b * NH + h) * SEQ + tt + r) * HD + d] = f32_bf16(acc[mi][ni][r] * 0.125f);
        } else if (sec == 1) {
#pragma unroll
          for (int r = 0; r < 4; ++r)
            Ko[(((size_t)b * NH + h) * SEQ + tt + r) * HD + d] = f32_bf16(acc[mi][ni][r]);
        } else {
          ushort4 o;
          o.x = f32_bf16(acc[mi][ni][0]); o.y = f32_bf16(acc[mi][ni][1]);
          o.z = f32_bf16(acc[mi][ni][2]); o.w = f32_bf16(acc[mi][ni][3]);
          *(ushort4*)&Vo[(((size_t)b * NH + h) * HD + d) * SEQ + tt] = o;  // V^T [b][h][d][t]
        }
      }
    }
  }
}

// ---------------- flash attention, causal, pair-balanced ----------------
// grid (QTILES/2, B*H); block 256 = 4 waves.
// Block i processes q-tiles {i, QTILES-1-i}: trip counts (i+1)+(QTILES-i) = 33 uniform,
// and 16*64=1024 blocks are fully co-resident (4 blk/CU, LDS-bound 5) -> no tail.
__global__ __launch_bounds__(256) void attn_k(
    const u16* __restrict__ Q, const u16* __restrict__ K,
    const u16* __restrict__ Vt_g,   // [B,H,HD,SEQ]
    u16* __restrict__ O)
{
  __shared__ u16 Ks[64][72];      // [key][d]
  __shared__ u16 Vt[64][72];      // [d][key]
  __shared__ u16 Ps[4][16][72];   // per wave: [qrow][key]
  int bh = blockIdx.y;
  int t = threadIdx.x, w = t >> 6, lane = t & 63;
  int m16 = lane & 15, quad = lane >> 4;
  int b = bh >> 4, h = bh & 15;

  int srow = t >> 2, sc = (t & 3) * 16;
  const u16* Kg0 = K    + ((size_t)bh * SEQ + srow) * HD  + sc;   // key=srow, d=sc..
  const u16* Vg0 = Vt_g + ((size_t)bh * HD  + srow) * SEQ + sc;   // d=srow,  key=sc..

  for (int half = 0; half < 2; ++half) {
    int qt = half ? (QTILES - 1 - (int)blockIdx.x) : (int)blockIdx.x;
    int q0 = qt * 64;

    const u16* Qb = Q + ((size_t)bh * SEQ + q0 + w * 16 + m16) * HD + quad * 8;
    s16x8 qf0 = *(const s16x8*)Qb;
    s16x8 qf1 = *(const s16x8*)(Qb + 32);

    f32x4 acco[4];
    float m_run[4], l_run[4];
#pragma unroll
    for (int r = 0; r < 4; ++r) { m_run[r] = -1e30f; l_run[r] = 0.f; }
#pragma unroll
    for (int ni = 0; ni < 4; ++ni)
#pragma unroll
      for (int r = 0; r < 4; ++r) acco[ni][r] = 0.f;

    for (int kt = 0; kt <= qt; ++kt) {
      uint4 kv0 = *(const uint4*)(Kg0 + (size_t)kt * 64 * HD);
      uint4 kv1 = *(const uint4*)(Kg0 + (size_t)kt * 64 * HD + 8);
      uint4 vv0 = *(const uint4*)(Vg0 + kt * 64);
      uint4 vv1 = *(const uint4*)(Vg0 + kt * 64 + 8);
      __syncthreads();   // previous tile's LDS reads done
      *(uint4*)&Ks[srow][sc]     = kv0;
      *(uint4*)&Ks[srow][sc + 8] = kv1;
      *(uint4*)&Vt[srow][sc]     = vv0;   // contiguous b128 — no transpose in-kernel
      *(uint4*)&Vt[srow][sc + 8] = vv1;
      __syncthreads();

      // S = Q K^T  (scale pre-folded into Q)
      f32x4 sacc[4];
#pragma unroll
      for (int ni = 0; ni < 4; ++ni)
#pragma unroll
        for (int r = 0; r < 4; ++r) sacc[ni][r] = 0.f;
#pragma unroll
      for (int ni = 0; ni < 4; ++ni) {
        s16x8 kf0 = *(const s16x8*)&Ks[ni * 16 + m16][quad * 8];
        s16x8 kf1 = *(const s16x8*)&Ks[ni * 16 + m16][32 + quad * 8];
        sacc[ni] = __builtin_amdgcn_mfma_f32_16x16x32_bf16(qf0, kf0, sacc[ni], 0, 0, 0);
        sacc[ni] = __builtin_amdgcn_mfma_f32_16x16x32_bf16(qf1, kf1, sacc[ni], 0, 0, 0);
      }
      if (kt == qt) {  // diagonal tile: causal mask
#pragma unroll
        for (int ni = 0; ni < 4; ++ni)
#pragma unroll
          for (int r = 0; r < 4; ++r) {
            int qrow = w * 16 + quad * 4 + r;
            int kcol = ni * 16 + m16;
            if (kcol > qrow) sacc[ni][r] = -1e30f;
          }
      }
      float rowm[4];
#pragma unroll
      for (int r = 0; r < 4; ++r) rowm[r] = -1e30f;
#pragma unroll
      for (int ni = 0; ni < 4; ++ni)
#pragma unroll
        for (int r = 0; r < 4; ++r) rowm[r] = fmaxf(rowm[r], sacc[ni][r]);
#pragma unroll
      for (int off = 1; off < 16; off <<= 1)
#pragma unroll
        for (int r = 0; r < 4; ++r) rowm[r] = fmaxf(rowm[r], __shfl_xor(rowm[r], off, 64));

      float alpha[4], psum[4];
#pragma unroll
      for (int r = 0; r < 4; ++r) {
        float mn = fmaxf(m_run[r], rowm[r]);
        alpha[r] = __expf(m_run[r] - mn);
        m_run[r] = mn;
        psum[r] = 0.f;
      }
#pragma unroll
      for (int ni = 0; ni < 4; ++ni)
#pragma unroll
        for (int r = 0; r < 4; ++r) {
          float p = __expf(sacc[ni][r] - m_run[r]);
          psum[r] += p;
          Ps[w][quad * 4 + r][ni * 16 + m16] = f32_bf16(p);
        }
#pragma unroll
      for (int off = 1; off < 16; off <<= 1)
#pragma unroll
        for (int r = 0; r < 4; ++r) psum[r] += __shfl_xor(psum[r], off, 64);
#pragma unroll
      for (int r = 0; r < 4; ++r) l_run[r] = l_run[r] * alpha[r] + psum[r];
#pragma unroll
      for (int ni = 0; ni < 4; ++ni)
#pragma unroll
        for (int r = 0; r < 4; ++r) acco[ni][r] *= alpha[r];

      // NO barrier here: Ps is written and read only by this wave; the compiler
      // orders same-array LDS write->read via lgkmcnt. Ks/Vt reads below are
      // covered by the post-staging barrier above.
#pragma unroll
      for (int ks = 0; ks < 2; ++ks) {
        s16x8 pf = *(const s16x8*)&Ps[w][m16][ks * 32 + quad * 8];
#pragma unroll
        for (int ni = 0; ni < 4; ++ni) {
          s16x8 vf = *(const s16x8*)&Vt[ni * 16 + m16][ks * 32 + quad * 8];
          acco[ni] = __builtin_amdgcn_mfma_f32_16x16x32_bf16(pf, vf, acco[ni], 0, 0, 0);
        }
      }
    }

    // epilogue: O / l, write as [B][T][H*HD] bf16
#pragma unroll
    for (int r = 0; r < 4; ++r) {
      float inv = 1.f / l_run[r];
      int trow = q0 + w * 16 + quad * 4 + r;
      size_t base = ((size_t)(b * SEQ + trow)) * DM + h * HD;
#pragma unroll
      for (int ni = 0; ni < 4; ++ni)
        O[base + ni * 16 + m16] = f32_bf16(acco[ni][r] * inv);
    }
  }
}

// ---------------- launch ----------------
extern "C" void kernel_launch(void* const* d_in, const int* in_sizes, int n_in,
                              void* d_out, int out_size, void* d_ws, size_t ws_size,
                              hipStream_t stream) {
  const float* x    = (const float*)d_in[0];   // [4,2048,1024]
  const float* Wqkv = (const float*)d_in[1];   // [1024,3072]
  const float* Wout = (const float*)d_in[2];   // [1024,1024]
  float* out = (float*)d_out;                  // [4,2048,1024] fp32

  u16* ws = (u16*)d_ws;
  size_t off = 0;
  u16* x_bf   = ws + off; off += (size_t)ROWS * DM;
  u16* wqkv_t = ws + off; off += (size_t)(3 * DM) * DM;
  u16* wout_t = ws + off; off += (size_t)DM * DM;
  u16* Qb     = ws + off; off += (size_t)BATCH * NH * SEQ * HD;
  u16* Kb     = ws + off; off += (size_t)BATCH * NH * SEQ * HD;
  u16* Vb     = ws + off; off += (size_t)BATCH * NH * SEQ * HD;  // [B,H,HD,T]
  u16* AO     = ws + off; off += (size_t)ROWS * DM;

  cast_bf16_k<<<(ROWS * DM / 4 + 255) / 256, 256, 0, stream>>>(x, x_bf, ROWS * DM / 4);
  cast_transpose_k<<<dim3(3 * DM / 32, DM / 32), 256, 0, stream>>>(Wqkv, wqkv_t, DM, 3 * DM);
  cast_transpose_k<<<dim3(DM / 32, DM / 32), 256, 0, stream>>>(Wout, wout_t, DM, DM);
  gemm_bt<1><<<dim3(3 * DM / 128, ROWS / 128), 256, 0, stream>>>(
      x_bf, wqkv_t, nullptr, Qb, Kb, Vb, ROWS, 3 * DM, DM);
  attn_k<<<dim3(QTILES / 2, BATCH * NH), 256, 0, stream>>>(Qb, Kb, Vb, AO);
  gemm_bt<0><<<dim3(DM / 128, ROWS / 128), 256, 0, stream>>>(
      AO, wout_t, out, nullptr, nullptr, nullptr, ROWS, DM, DM);
}